// Round 5
// baseline (708.724 us; speedup 1.0000x reference)
//
#include <hip/hip_runtime.h>
#include <math.h>

#define BB 8
#define LL 4096
#define DD 512
#define PTOT (BB*LL)      // 32768 positions
#define HID  2048

typedef __attribute__((ext_vector_type(8))) short short8;   // 8 bf16 (4 VGPRs)
typedef __attribute__((ext_vector_type(4))) float f32x4;

typedef __attribute__((address_space(1))) const unsigned int gconst_u32;
typedef __attribute__((address_space(3))) unsigned int lds_u32;

__device__ __forceinline__ void gload16(const void* g, void* l) {
    // async global->LDS DMA, 16B per lane; LDS dest = wave-uniform base + lane*16
    __builtin_amdgcn_global_load_lds((gconst_u32*)g, (lds_u32*)l, 16, 0, 0);
}

__device__ __forceinline__ unsigned short f2bf(float f) {
    union { float f; unsigned int u; } v; v.f = f;
    unsigned int r = v.u + 0x7fffu + ((v.u >> 16) & 1u);
    return (unsigned short)(r >> 16);
}
__device__ __forceinline__ float bf2f(unsigned short h) {
    union { unsigned int u; float f; } v; v.u = ((unsigned int)h) << 16;
    return v.f;
}
// gelu(x) = x * sigmoid(2*0.79788456*(x + 0.044715 x^3)); HW exp/rcp
__device__ __forceinline__ float gelu_fast(float x) {
    float x2 = x * x;
    float t  = x * fmaf(0.044715f, x2, 1.0f);
    float e  = __builtin_amdgcn_exp2f(-2.3021143f * t);   // e^{-2z}
    return x * __builtin_amdgcn_rcpf(1.0f + e);
}

// ---------------------------------------------------------------------------
// x fp32 -> bf16
__global__ __launch_bounds__(256) void convert_x(const float* __restrict__ x,
                                                 unsigned short* __restrict__ xb) {
    int tid = blockIdx.x * 256 + threadIdx.x;
    float4 v = ((const float4*)x)[tid];
    uint2 o;
    o.x = (unsigned int)f2bf(v.x) | ((unsigned int)f2bf(v.y) << 16);
    o.y = (unsigned int)f2bf(v.z) | ((unsigned int)f2bf(v.w) << 16);
    ((uint2*)xb)[tid] = o;
}

// conv W (o,c,k) -> Wt[o][k*512+c] bf16
__global__ __launch_bounds__(256) void trans_wconv(const float* __restrict__ W,
                                                   unsigned short* __restrict__ Wt, int K) {
    int tid = blockIdx.x * 256 + threadIdx.x;
    if (tid >= DD * DD * K) return;
    int o  = tid / (K * DD);
    int kc = tid - o * K * DD;
    int k  = kc >> 9;
    int c  = kc & (DD - 1);
    Wt[tid] = f2bf(W[(o * DD + c) * K + k]);
}

// mlp_w1 (c, n) -> W1t[n][c]
__global__ __launch_bounds__(256) void trans_w1(const float* __restrict__ W,
                                                unsigned short* __restrict__ Wt) {
    int tid = blockIdx.x * 256 + threadIdx.x;   // n*512 + c
    int n = tid >> 9;
    int c = tid & (DD - 1);
    Wt[tid] = f2bf(W[c * HID + n]);
}

// mlp_w2 (h, n) -> W2t[n][h]
__global__ __launch_bounds__(256) void trans_w2(const float* __restrict__ W,
                                                unsigned short* __restrict__ Wt) {
    int tid = blockIdx.x * 256 + threadIdx.x;   // n*2048 + h
    int n = tid >> 11;
    int h = tid & (HID - 1);
    Wt[tid] = f2bf(W[h * DD + n]);
}

// maskb[p] bit (d+3), d=-3..3: in-range && chain match. Serves K=3/5/7.
// Also zeros the 256B zero-page (ws re-poisoned each launch).
__global__ __launch_bounds__(256) void make_maskb(const int* __restrict__ chain,
                                                  unsigned char* __restrict__ mb,
                                                  unsigned short* __restrict__ zp) {
    int p = blockIdx.x * 256 + threadIdx.x;
    if (blockIdx.x == 0 && threadIdx.x < 128) zp[threadIdx.x] = 0;
    int b = p >> 12;
    int l = p & (LL - 1);
    int c0 = chain[p];
    unsigned m = 0;
#pragma unroll
    for (int d = -3; d <= 3; d++) {
        int l2 = l + d;
        bool ok = (l2 >= 0) && (l2 < LL) && (chain[b * LL + l2] == c0);
        m |= (ok ? 1u : 0u) << (d + 3);
    }
    mb[p] = (unsigned char)m;
}

// ---------------------------------------------------------------------------
// Conv MFMA kernel: block 128x128, BK=64, 4 waves (2x2), wave tile 64x64.
// A halo (144 rows x 64ch, rows p0-8..p0+135) staged ONCE per channel chunk;
// all K taps read it at row offset d with per-row mask via cndmask.
// B (weights, L2-hot) ping-pong staged per tap; the per-tap barrier drains
// only 4 small L2 loads that overlapped the previous tap's 32 MFMAs.
// XOR-swizzled LDS rows (128B row, quad qq at slot qq^(r&7)) -> 2-way only.
template <int K>
__global__ __launch_bounds__(256, 3) void conv_mfma(
        const unsigned short* __restrict__ A,       // [PTOT][512] bf16
        const unsigned char* __restrict__ maskb,    // [PTOT]
        const unsigned short* __restrict__ Bt,      // [512][K*512] bf16
        const float* __restrict__ bias,
        unsigned short* __restrict__ Y,             // [PTOT][512] bf16
        const unsigned short* __restrict__ zp) {
    const int PAD = (K - 1) / 2;
    const int LDB = K * DD;
    __shared__ alignas(16) unsigned short As[144 * 64];      // 18 KB halo
    __shared__ alignas(16) unsigned short Bs[2][128 * 64];   // 2 x 16 KB ping-pong

    int t = threadIdx.x;
    int p0 = blockIdx.x * 128;
    int o0 = blockIdx.y * 128;
    int w = t >> 6, lane = t & 63;
    int wr = w & 1, wc = w >> 1;
    int lm = lane & 15, q = lane >> 4;
    int lrow8 = lane >> 3;                  // row-within-8 for staging
    int qq = (lane & 7) ^ lrow8;            // source quad (slot = lane&7)

    // mask bits for this lane's 4 output-row groups
    unsigned int mbits[4];
#pragma unroll
    for (int mi = 0; mi < 4; mi++)
        mbits[mi] = maskb[p0 + wr * 64 + mi * 16 + lm];

    // B staging: wave w stages rows [w*32, w*32+32), 4 instrs x 8 rows
    size_t brow[4];
#pragma unroll
    for (int j = 0; j < 4; j++)
        brow[j] = (size_t)(o0 + w * 32 + j * 8 + lrow8) * LDB + qq * 8;

    // A halo staging: 18 chunks of 8 rows; wave w takes chunks w+4i, plus 16+w (w<2)
    const unsigned short* agp[5];
    int nch = (w < 2) ? 5 : 4;
#pragma unroll
    for (int i = 0; i < 5; i++) {
        int c = (i < 4) ? (w + 4 * i) : (16 + w);
        int gr = p0 - 8 + c * 8 + lrow8;
        agp[i] = (gr >= 0 && gr < PTOT) ? (A + (size_t)gr * DD + qq * 8) : zp;
    }

    f32x4 acc[4][4];
#pragma unroll
    for (int mi = 0; mi < 4; mi++)
#pragma unroll
        for (int nj = 0; nj < 4; nj++) acc[mi][nj] = (f32x4){0.f, 0.f, 0.f, 0.f};

    for (int kc = 0; kc < DD; kc += 64) {
        // stage A halo for this channel chunk
        for (int i = 0; i < nch; i++) {
            int c = (i < 4) ? (w + 4 * i) : (16 + w);
            const unsigned short* g = agp[i];
            gload16((g == zp) ? g : (g + kc), As + c * 512);
        }
        // stage B tap 0
#pragma unroll
        for (int j = 0; j < 4; j++)
            gload16(Bt + brow[j] + kc, Bs[0] + w * 2048 + j * 512);
        __syncthreads();

        for (int tap = 0; tap < K; tap++) {
            int cur = tap & 1;
            if (tap + 1 < K) {  // prefetch next tap's B into the other buffer
#pragma unroll
                for (int j = 0; j < 4; j++)
                    gload16(Bt + brow[j] + (size_t)(tap + 1) * DD + kc,
                            Bs[cur ^ 1] + w * 2048 + j * 512);
            }
            int d  = tap - PAD;           // row shift
            int mb = tap - PAD + 3;       // mask bit index
            bool keep[4];
#pragma unroll
            for (int mi = 0; mi < 4; mi++) keep[mi] = (mbits[mi] >> mb) & 1;
            int rm = (lm + d) & 7;        // (read row)&7 for swizzle

#pragma unroll
            for (int kk = 0; kk < 2; kk++) {
                int slot = kk * 4 + q;
                int sab = (slot ^ (lm & 7)) * 8;
                int saa = (slot ^ rm) * 8;
                short8 b[4];
#pragma unroll
                for (int nj = 0; nj < 4; nj++)
                    b[nj] = *(const short8*)&Bs[cur][(wc * 64 + nj * 16 + lm) * 64 + sab];
#pragma unroll
                for (int mi = 0; mi < 4; mi++) {
                    int hr = 8 + wr * 64 + mi * 16 + lm + d;
                    short8 a = *(const short8*)&As[hr * 64 + saa];
                    short8 zero = {};
                    a = keep[mi] ? a : zero;
#pragma unroll
                    for (int nj = 0; nj < 4; nj++)
                        acc[mi][nj] = __builtin_amdgcn_mfma_f32_16x16x32_bf16(
                            a, b[nj], acc[mi][nj], 0, 0, 0);
                }
            }
            __syncthreads();
        }
    }

    // epilogue: C/D layout col=lane&15, row=(lane>>4)*4+reg  [m89-verified]
#pragma unroll
    for (int mi = 0; mi < 4; mi++) {
#pragma unroll
        for (int nj = 0; nj < 4; nj++) {
            int col = o0 + wc * 64 + nj * 16 + lm;
#pragma unroll
            for (int r = 0; r < 4; r++) {
                int row = p0 + wr * 64 + mi * 16 + q * 4 + r;
                Y[(size_t)row * DD + col] = f2bf(acc[mi][nj][r] + bias[col]);
            }
        }
    }
}

// ---------------------------------------------------------------------------
// Plain MFMA GEMM for MLP: block 128x128, BK=64, wave tile 64x64.
// EPI: 1 = bf16 out = gelu(acc+bias); 2 = f32 out = acc+bias; 3 = f32 out += acc.
template <int EPI>
__global__ __launch_bounds__(256, 3) void mfma_gemm(
        const unsigned short* __restrict__ A, int lda,
        const unsigned short* __restrict__ Bt, int ldb,
        const float* __restrict__ bias,
        void* __restrict__ Yv, int ldc, int Kspan) {
    __shared__ alignas(16) unsigned short As[128 * 64];   // 16 KB, swizzled
    __shared__ alignas(16) unsigned short Bs[128 * 64];   // 16 KB, swizzled

    int t = threadIdx.x;
    int p0 = blockIdx.x * 128;
    int o0 = blockIdx.y * 128;
    int w = t >> 6, lane = t & 63;
    int wr = w & 1, wc = w >> 1;
    int lm = lane & 15, q = lane >> 4;
    int lrow8 = lane >> 3;
    int qq = (lane & 7) ^ lrow8;

    unsigned short* a_dst = As + w * 2048;
    unsigned short* b_dst = Bs + w * 2048;

    int aoff[4], boff[4];
#pragma unroll
    for (int i = 0; i < 4; i++) {
        aoff[i] = (p0 + w * 32 + i * 8 + lrow8) * lda + qq * 8;
        boff[i] = (o0 + w * 32 + i * 8 + lrow8) * ldb + qq * 8;
    }

    f32x4 acc[4][4];
#pragma unroll
    for (int mi = 0; mi < 4; mi++)
#pragma unroll
        for (int nj = 0; nj < 4; nj++) acc[mi][nj] = (f32x4){0.f, 0.f, 0.f, 0.f};

    for (int kc = 0; kc < Kspan; kc += 64) {
#pragma unroll
        for (int i = 0; i < 4; i++) {
            gload16(A + aoff[i] + kc, a_dst + i * 512);
            gload16(Bt + boff[i] + kc, b_dst + i * 512);
        }
        __syncthreads();
#pragma unroll
        for (int kk = 0; kk < 2; kk++) {
            int sa = ((kk * 4 + q) ^ (lm & 7)) * 8;
            short8 b[4];
#pragma unroll
            for (int nj = 0; nj < 4; nj++)
                b[nj] = *(const short8*)&Bs[(wc * 64 + nj * 16 + lm) * 64 + sa];
#pragma unroll
            for (int mi = 0; mi < 4; mi++) {
                short8 a = *(const short8*)&As[(wr * 64 + mi * 16 + lm) * 64 + sa];
#pragma unroll
                for (int nj = 0; nj < 4; nj++)
                    acc[mi][nj] = __builtin_amdgcn_mfma_f32_16x16x32_bf16(
                        a, b[nj], acc[mi][nj], 0, 0, 0);
            }
        }
        __syncthreads();
    }

#pragma unroll
    for (int mi = 0; mi < 4; mi++) {
#pragma unroll
        for (int nj = 0; nj < 4; nj++) {
            int col = o0 + wc * 64 + nj * 16 + lm;
#pragma unroll
            for (int r = 0; r < 4; r++) {
                int row = p0 + wr * 64 + mi * 16 + q * 4 + r;
                float v = acc[mi][nj][r];
                size_t idx = (size_t)row * ldc + col;
                if (EPI == 1) {
                    ((unsigned short*)Yv)[idx] = f2bf(gelu_fast(v + bias[col]));
                } else if (EPI == 2) {
                    ((float*)Yv)[idx] = v + bias[col];
                } else {
                    ((float*)Yv)[idx] += v;
                }
            }
        }
    }
}

// ---------------------------------------------------------------------------
// LN1: out_bf16 = LN(x_f32 + conv_bf16)
__global__ __launch_bounds__(256) void ln1_kernel(const float* __restrict__ x,
                                                  const unsigned short* __restrict__ conv,
                                                  const float* __restrict__ g,
                                                  const float* __restrict__ beta,
                                                  unsigned short* __restrict__ h) {
    int p = blockIdx.x, t = threadIdx.x;
    size_t base = (size_t)p * DD;
    float v0 = x[base + t] + bf2f(conv[base + t]);
    float v1 = x[base + 256 + t] + bf2f(conv[base + 256 + t]);
    float s = v0 + v1, sq = v0 * v0 + v1 * v1;
#pragma unroll
    for (int off = 32; off > 0; off >>= 1) { s += __shfl_xor(s, off); sq += __shfl_xor(sq, off); }
    __shared__ float red[2][4];
    int wid = t >> 6, lane = t & 63;
    if (lane == 0) { red[0][wid] = s; red[1][wid] = sq; }
    __syncthreads();
    float S = red[0][0] + red[0][1] + red[0][2] + red[0][3];
    float SQ = red[1][0] + red[1][1] + red[1][2] + red[1][3];
    float mu = S * (1.f / DD);
    float var = SQ * (1.f / DD) - mu * mu;
    float rs = rsqrtf(var + 1e-5f);
    h[base + t]       = f2bf((v0 - mu) * rs * g[t] + beta[t]);
    h[base + 256 + t] = f2bf((v1 - mu) * rs * g[256 + t] + beta[256 + t]);
}

// LN2: out_f32 = LN(h_bf16 + out_f32) in place
__global__ __launch_bounds__(256) void ln2_kernel(const unsigned short* __restrict__ h,
                                                  float* __restrict__ out,
                                                  const float* __restrict__ g,
                                                  const float* __restrict__ beta) {
    int p = blockIdx.x, t = threadIdx.x;
    size_t base = (size_t)p * DD;
    float v0 = bf2f(h[base + t]) + out[base + t];
    float v1 = bf2f(h[base + 256 + t]) + out[base + 256 + t];
    float s = v0 + v1, sq = v0 * v0 + v1 * v1;
#pragma unroll
    for (int off = 32; off > 0; off >>= 1) { s += __shfl_xor(s, off); sq += __shfl_xor(sq, off); }
    __shared__ float red[2][4];
    int wid = t >> 6, lane = t & 63;
    if (lane == 0) { red[0][wid] = s; red[1][wid] = sq; }
    __syncthreads();
    float S = red[0][0] + red[0][1] + red[0][2] + red[0][3];
    float SQ = red[1][0] + red[1][1] + red[1][2] + red[1][3];
    float mu = S * (1.f / DD);
    float var = SQ * (1.f / DD) - mu * mu;
    float rs = rsqrtf(var + 1e-5f);
    out[base + t]       = (v0 - mu) * rs * g[t] + beta[t];
    out[base + 256 + t] = (v1 - mu) * rs * g[256 + t] + beta[256 + t];
}

// ---------------------------------------------------------------------------
extern "C" void kernel_launch(void* const* d_in, const int* in_sizes, int n_in,
                              void* d_out, int out_size, void* d_ws, size_t ws_size,
                              hipStream_t stream) {
    const float* x     = (const float*)d_in[0];
    const int*   chain = (const int*)d_in[1];
    const float* W3    = (const float*)d_in[2];
    const float* b3    = (const float*)d_in[3];
    const float* W5    = (const float*)d_in[4];
    const float* b5    = (const float*)d_in[5];
    const float* W7    = (const float*)d_in[6];
    const float* b7    = (const float*)d_in[7];
    const float* w1    = (const float*)d_in[8];
    const float* bm1   = (const float*)d_in[9];
    const float* w2    = (const float*)d_in[10];
    const float* bm2   = (const float*)d_in[11];
    const float* g1    = (const float*)d_in[12];
    const float* be1   = (const float*)d_in[13];
    const float* g2    = (const float*)d_in[14];
    const float* be2   = (const float*)d_in[15];
    float* out = (float*)d_out;

    const size_t ACT = (size_t)PTOT * DD * 2;     // 32 MB bf16 activation buffer
    char* ws = (char*)d_ws;
    size_t off = 0;
    unsigned short* Xb   = (unsigned short*)(ws + off); off += ACT;
    unsigned short* buf1 = (unsigned short*)(ws + off); off += ACT;
    unsigned short* buf2 = (unsigned short*)(ws + off); off += ACT;
    unsigned short* w3t  = (unsigned short*)(ws + off); off += (size_t)3 * DD * DD * 2;
    unsigned short* w5t  = (unsigned short*)(ws + off); off += (size_t)5 * DD * DD * 2;
    unsigned short* w7t  = (unsigned short*)(ws + off); off += (size_t)7 * DD * DD * 2;
    unsigned short* w1t  = (unsigned short*)(ws + off); off += (size_t)DD * HID * 2;
    unsigned short* w2t  = (unsigned short*)(ws + off); off += (size_t)DD * HID * 2;
    unsigned char* maskb = (unsigned char*)(ws + off); off += PTOT;
    unsigned short* zp   = (unsigned short*)(ws + off); off += 256;
    size_t base_off = off;
    bool full = (ws_size >= base_off + (size_t)PTOT * HID * 2);
    unsigned short* Hb = (unsigned short*)(ws + base_off);  // 32MB chunked / 128MB full

    // prep
    convert_x<<<PTOT * DD / (256 * 4), 256, 0, stream>>>(x, Xb);
    trans_wconv<<<(DD * DD * 3 + 255) / 256, 256, 0, stream>>>(W3, w3t, 3);
    trans_wconv<<<(DD * DD * 5 + 255) / 256, 256, 0, stream>>>(W5, w5t, 5);
    trans_wconv<<<(DD * DD * 7 + 255) / 256, 256, 0, stream>>>(W7, w7t, 7);
    trans_w1<<<DD * HID / 256, 256, 0, stream>>>(w1, w1t);
    trans_w2<<<DD * HID / 256, 256, 0, stream>>>(w2, w2t);
    make_maskb<<<PTOT / 256, 256, 0, stream>>>(chain, maskb, zp);

    dim3 gconv(PTOT / 128, DD / 128);   // 256 x 4

    conv_mfma<3><<<gconv, 256, 0, stream>>>(Xb, maskb, w3t, b3, buf1, zp);
    conv_mfma<5><<<gconv, 256, 0, stream>>>(buf1, maskb, w5t, b5, buf2, zp);
    conv_mfma<7><<<gconv, 256, 0, stream>>>(buf2, maskb, w7t, b7, buf1, zp);

    ln1_kernel<<<PTOT, 256, 0, stream>>>(x, buf1, g1, be1, buf2);

    if (full) {
        dim3 g1d(PTOT / 128, HID / 128);   // 256 x 16
        mfma_gemm<1><<<g1d, 256, 0, stream>>>(buf2, DD, w1t, DD, bm1, Hb, HID, DD);
        mfma_gemm<2><<<gconv, 256, 0, stream>>>(Hb, HID, w2t, HID, bm2, out, DD, HID);
    } else {
        for (int jc = 0; jc < 4; jc++) {
            mfma_gemm<1><<<gconv, 256, 0, stream>>>(buf2, DD, w1t + (size_t)jc * DD * DD,
                                                    DD, bm1 + jc * DD, Hb, DD, DD);
            if (jc == 0)
                mfma_gemm<2><<<gconv, 256, 0, stream>>>(Hb, DD, w2t + jc * DD, HID, bm2,
                                                        out, DD, DD);
            else
                mfma_gemm<3><<<gconv, 256, 0, stream>>>(Hb, DD, w2t + jc * DD, HID, bm2,
                                                        out, DD, DD);
        }
    }

    ln2_kernel<<<PTOT, 256, 0, stream>>>(buf2, out, g2, be2);
}